// Round 8
// baseline (205.700 us; speedup 1.0000x reference)
//
#include <hip/hip_runtime.h>
#include <hip/hip_fp16.h>

// NCC loss: 9^3 box sums of {I, J, I*I, J*J, I*J}, per-voxel cc, -mean(cc).
// Dims: C=2, D=192, H=224, W=192, fp32. Separable box filter:
//   K1 (k_hwsum): H-sum (register ring, 1-step prefetch) + W-sum (LDS 9-tap,
//                 double-buffered, one barrier per h-step) -> fp16 2D sums.
//   K2 (k_dsum):  D-sum — barrier-free streaming register ring + cc + reduce.
// KEY: D-chunked with Dc=48 so the fp16 intermediate (48 MB) + input slab
// (33 MB) stay L3-resident (256 MB). The buffer is re-used at the SAME
// addresses every chunk -> K1 writes update dirty L3 lines (no HBM write),
// K2 reads hit L3. Targets the ~2.9 TB/s L3-thrash cap seen in rounds 2-7.

#define C2   2
#define DDIM 192
#define HDIM 224
#define WDIM 192
#define HWN  (HDIM*WDIM)              // 43008
#define VOL  ((size_t)DDIM*HWN)       // 8257536
#define RAD  4
#define WINV (1.0f/729.0f)

#define HT1  14   // K1 h-chunk per block (224/14 = 16 strips -> parallelism per chunk)

// ---------------- K1: H-sum + W-sum of 5 product fields ----------------
// grid: (d rows in [dbeg,dend), HDIM/HT1, C2); block: 192 threads (w)
// buf layout (fp16): [f][c][bd][h][w], bd = d - d0 + 4, fstride = C2*bufD*HWN
__global__ __launch_bounds__(192)
void k_hwsum(const float* __restrict__ I, const float* __restrict__ J,
             __half* __restrict__ buf, int d0, int dbeg, int bufD)
{
    const int w  = threadIdx.x;
    const int d  = dbeg + blockIdx.x;
    const int h0 = blockIdx.y * HT1;
    const int c  = blockIdx.z;

    __shared__ float row[2][5][WDIM + 8];   // double-buffered H-sum row, 8 KB
    if (w < 8) {                            // zero the W-halo pads once
        const int pos = (w < 4) ? w : (WDIM + w);
        #pragma unroll
        for (int b = 0; b < 2; ++b)
            #pragma unroll
            for (int f = 0; f < 5; ++f) row[b][f][pos] = 0.f;
    }
    __syncthreads();

    const float* Ib = I + (size_t)c*VOL + (size_t)d*HWN + w;
    const float* Jb = J + (size_t)c*VOL + (size_t)d*HWN + w;

    float ring[5][9];
    float rs[5] = {0.f,0.f,0.f,0.f,0.f};

    // warm-up: ring slots 0..7 = products at rows h0-4 .. h0+3 (zero padded)
    #pragma unroll
    for (int k = 0; k < 8; ++k) {
        const int h = h0 - RAD + k;
        float iv = 0.f, jv = 0.f;
        if (h >= 0 && h < HDIM) { iv = Ib[(size_t)h*WDIM]; jv = Jb[(size_t)h*WDIM]; }
        const float pr[5] = {iv, jv, iv*iv, jv*jv, iv*jv};
        #pragma unroll
        for (int f = 0; f < 5; ++f) { ring[f][k] = pr[f]; rs[f] += pr[f]; }
    }

    // one-step prefetch of row h0+4
    float niv = 0.f, njv = 0.f;
    {
        const int hf = h0 + RAD;
        if (hf < HDIM) { niv = Ib[(size_t)hf*WDIM]; njv = Jb[(size_t)hf*WDIM]; }
    }

    const size_t fstride = (size_t)C2*bufD*HWN;
    __half* ob = buf + ((size_t)c*bufD + (size_t)(d - d0 + RAD))*HWN + w;

    int i = 0;
    while (i < HT1) {
        #pragma unroll
        for (int p = 0; p < 9; ++p) {   // i == p (mod 9) whenever body runs
            if (i < HT1) {
                const int h  = h0 + i;
                const float iv = niv, jv = njv;
                // prefetch next step's row (hides latency under LDS phase)
                niv = 0.f; njv = 0.f;
                const int hf2 = h + 1 + RAD;
                if (i + 1 < HT1 && hf2 < HDIM) {
                    niv = Ib[(size_t)hf2*WDIM]; njv = Jb[(size_t)hf2*WDIM];
                }
                const float pr[5] = {iv, jv, iv*iv, jv*jv, iv*jv};
                float (* __restrict__ rb)[WDIM+8] = row[h & 1];
                #pragma unroll
                for (int f = 0; f < 5; ++f) {
                    rs[f] += pr[f];                 // H window sum at h
                    rb[f][RAD + w] = rs[f];
                    rs[f] -= ring[f][p];            // drop row h-4
                    ring[f][(p+8)%9] = pr[f];       // keep row h+4
                }
                __syncthreads();                    // single barrier: dbuf-safe
                #pragma unroll
                for (int f = 0; f < 5; ++f) {
                    float s = 0.f;
                    #pragma unroll
                    for (int q = 0; q < 9; ++q) s += rb[f][w + q];
                    ob[(size_t)f*fstride + (size_t)h*WDIM] = __float2half(s);
                }
                ++i;
            }
        }
    }
}

// -------- K2: D-sum (register ring) + cc + block reduce — no LDS, no syncs --------
// grid: (HWN/256, nsub, C2); block: 256 threads
__global__ __launch_bounds__(256)
void k_dsum(const __half* __restrict__ buf, double* __restrict__ gacc,
            int d0, int bufD, int DS)
{
    const int tid = threadIdx.x;
    const int pix = blockIdx.x*256 + tid;     // (h,w) flat, HWN = 168*256 exact
    const int c   = blockIdx.z;
    const int ds0 = d0 + blockIdx.y*DS;

    const size_t fstride = (size_t)C2*bufD*HWN;
    const __half* base = buf + (size_t)c*bufD*HWN + pix;

    float ring[5][9];
    float rs[5] = {0.f,0.f,0.f,0.f,0.f};
    float acc = 0.f;

    // warm-up: slices ds0-4 .. ds0+3
    #pragma unroll
    for (int k = 0; k < 8; ++k) {
        const int dd = ds0 - RAD + k;
        float v[5] = {0.f,0.f,0.f,0.f,0.f};
        if ((unsigned)dd < (unsigned)DDIM) {
            const __half* pp = base + (size_t)(dd - d0 + RAD)*HWN;
            #pragma unroll
            for (int f = 0; f < 5; ++f) v[f] = __half2float(pp[(size_t)f*fstride]);
        }
        #pragma unroll
        for (int f = 0; f < 5; ++f) { ring[f][k] = v[f]; rs[f] += v[f]; }
    }

    int i = 0;
    while (i < DS) {
        #pragma unroll
        for (int p = 0; p < 9; ++p) {   // i == p (mod 9) whenever body runs
            if (i < DS) {
                const int dd = ds0 + i + RAD;
                float v[5] = {0.f,0.f,0.f,0.f,0.f};
                if (dd < DDIM) {
                    const __half* pp = base + (size_t)(dd - d0 + RAD)*HWN;
                    #pragma unroll
                    for (int f = 0; f < 5; ++f) v[f] = __half2float(pp[(size_t)f*fstride]);
                }
                float S[5];
                #pragma unroll
                for (int f = 0; f < 5; ++f) {
                    rs[f] += v[f];              // full 9x9x9 sum at dd-4
                    S[f] = rs[f];
                    rs[f] -= ring[f][p];        // drop slice dd-8
                    ring[f][(p+8)%9] = v[f];    // keep slice dd
                }
                const float uI    = S[0]*WINV;
                const float uJ    = S[1]*WINV;
                const float cross = S[4] - uJ*S[0];
                const float Iv    = S[2] - uI*S[0];
                const float Jv    = S[3] - uJ*S[1];
                acc += cross*cross / (Iv*Jv + 1e-5f);
                ++i;
            }
        }
    }

    // block reduction -> one double atomic per block
    __shared__ float wred[4];
    #pragma unroll
    for (int off = 32; off > 0; off >>= 1) acc += __shfl_down(acc, off);
    if ((tid & 63) == 0) wred[tid >> 6] = acc;
    __syncthreads();
    if (tid == 0) {
        const float sum = wred[0] + wred[1] + wred[2] + wred[3];
        atomicAdd(gacc, (double)sum);
    }
}

__global__ void k_fin(const double* __restrict__ gacc, float* __restrict__ out)
{
    out[0] = (float)(-gacc[0] / (double)((size_t)C2*DDIM*HDIM*WDIM));
}

extern "C" void kernel_launch(void* const* d_in, const int* in_sizes, int n_in,
                              void* d_out, int out_size, void* d_ws, size_t ws_size,
                              hipStream_t stream)
{
    if (n_in < 2) return;
    const float* I = (const float*)d_in[0];
    const float* J = (const float*)d_in[1];
    float* out = (float*)d_out;
    double* gacc = (double*)d_ws;
    __half* buf = (__half*)((char*)d_ws + 256);

    // D-chunk: capped at 48 so chunk buffer (48 MB) + input slab stay L3-resident
    static const int cands[] = {48, 24, 12, 6, 4, 2, 1};
    int Dc = 0;
    for (int c : cands) {
        const size_t need = 256 + (size_t)5*C2*(c+8)*HWN*sizeof(__half);
        if (need <= ws_size) { Dc = c; break; }
    }
    if (Dc == 0) return;  // ws too small — cannot run

    hipMemsetAsync(d_ws, 0, 256, stream);   // zero the double accumulator

    const int DS   = (Dc % 12 == 0) ? 12 : Dc;  // K2 sub-chunk along D
    const int nsub = Dc / DS;
    const int bufD = Dc + 8;

    for (int d0 = 0; d0 < DDIM; d0 += Dc) {
        const int dbeg = (d0 - RAD < 0) ? 0 : d0 - RAD;
        const int dend = (d0 + Dc + RAD > DDIM) ? DDIM : d0 + Dc + RAD;
        dim3 g1(dend - dbeg, HDIM/HT1, C2);
        k_hwsum<<<g1, dim3(192,1,1), 0, stream>>>(I, J, buf, d0, dbeg, bufD);
        dim3 g2(HWN/256, nsub, C2);
        k_dsum<<<g2, dim3(256,1,1), 0, stream>>>(buf, gacc, d0, bufD, DS);
    }
    k_fin<<<1,1,0,stream>>>(gacc, out);
}

// Round 9
// 111.550 us; speedup vs baseline: 1.8440x; 1.8440x over previous
//
#include <hip/hip_runtime.h>
#include <hip/hip_fp16.h>

// NCC loss: 9^3 box sums of {I, J, I*I, J*J, I*J}, per-voxel cc, -mean(cc).
// Dims: C=2, D=192, H=224, W=192, fp32. Full-volume two-pass:
//   K1 (k_hwsum): wave = one d-row. 48 active lanes x 4 px = W=192.
//     H-sum: running float4 sums + 9-deep NAMED-register I/J ring (static
//     indexing via 9-phase macro; drop-row products recomputed).
//     W-sum: wave-private LDS row, 5 ds_write_b128 + 10 ds_read_b128 per
//     192 px (vs 150 b32-equiv ops before) — attacks the LDS-pipe issue
//     bound identified as the ~2.9 TB/s cap across rounds 2-6.
//     No barriers (same-wave LDS is in-order; lgkmcnt only).
//   K2 (k_dsum): D-sum — barrier-free streaming register ring + cc + reduce.

#define C2   2
#define DDIM 192
#define HDIM 224
#define WDIM 192
#define HWN  (HDIM*WDIM)              // 43008
#define VOL  ((size_t)DDIM*HWN)       // 8257536
#define RAD  4
#define WINV (1.0f/729.0f)

#define HT1  28   // h-strip per wave (224/28 = 8 strips); 28 = 3*9 + 1 phases

__device__ __forceinline__ float4 zero4() { float4 z; z.x=z.y=z.z=z.w=0.f; return z; }

__device__ __forceinline__ void padd(float4& r0, float4& r1, float4& r2,
                                     float4& r3, float4& r4,
                                     const float4 a, const float4 b) {
    r0.x+=a.x; r0.y+=a.y; r0.z+=a.z; r0.w+=a.w;
    r1.x+=b.x; r1.y+=b.y; r1.z+=b.z; r1.w+=b.w;
    r2.x=fmaf(a.x,a.x,r2.x); r2.y=fmaf(a.y,a.y,r2.y);
    r2.z=fmaf(a.z,a.z,r2.z); r2.w=fmaf(a.w,a.w,r2.w);
    r3.x=fmaf(b.x,b.x,r3.x); r3.y=fmaf(b.y,b.y,r3.y);
    r3.z=fmaf(b.z,b.z,r3.z); r3.w=fmaf(b.w,b.w,r3.w);
    r4.x=fmaf(a.x,b.x,r4.x); r4.y=fmaf(a.y,b.y,r4.y);
    r4.z=fmaf(a.z,b.z,r4.z); r4.w=fmaf(a.w,b.w,r4.w);
}
__device__ __forceinline__ void psub(float4& r0, float4& r1, float4& r2,
                                     float4& r3, float4& r4,
                                     const float4 a, const float4 b) {
    r0.x-=a.x; r0.y-=a.y; r0.z-=a.z; r0.w-=a.w;
    r1.x-=b.x; r1.y-=b.y; r1.z-=b.z; r1.w-=b.w;
    r2.x=fmaf(-a.x,a.x,r2.x); r2.y=fmaf(-a.y,a.y,r2.y);
    r2.z=fmaf(-a.z,a.z,r2.z); r2.w=fmaf(-a.w,a.w,r2.w);
    r3.x=fmaf(-b.x,b.x,r3.x); r3.y=fmaf(-b.y,b.y,r3.y);
    r3.z=fmaf(-b.z,b.z,r3.z); r3.w=fmaf(-b.w,b.w,r3.w);
    r4.x=fmaf(-a.x,b.x,r4.x); r4.y=fmaf(-a.y,b.y,r4.y);
    r4.z=fmaf(-a.z,b.z,r4.z); r4.w=fmaf(-a.w,b.w,r4.w);
}

// ---------------- K1: H-sum + W-sum of 5 product fields ----------------
// grid: ((nd+3)/4, HDIM/HT1, C2); block: 256 = 4 waves = 4 consecutive d-slices
// buf layout (fp16): [f][c][bd][h][w], bd = d - d0 + 4, fstride = C2*bufD*HWN
// LDS per wave: 5 fields x 208 floats; float4 view: idx k+1|k+2|k+3 = window.
__global__ __launch_bounds__(256)
void k_hwsum(const float* __restrict__ I, const float* __restrict__ J,
             __half* __restrict__ buf, int d0, int dbeg, int dend, int bufD)
{
    const int tid = threadIdx.x;
    const int wv  = tid >> 6;
    const int k   = tid & 63;
    const bool act = (k < 48);
    const int w0  = 4 * (act ? k : 0);
    int d = dbeg + 4*blockIdx.x + wv;
    if (d >= dend) d = dend - 1;      // duplicate wave writes identical data
    const int h0 = blockIdx.y * HT1;
    const int c  = blockIdx.z;

    __shared__ float lds[4][5][208];  // [wave][field][4pad | 4..196 | 4pad | 4], 16.6 KB

    // zero W-halo pads: fi 4..7 (w=-4..-1) and fi 200..203 (w=192..195)
    if (k < 4) {
        #pragma unroll
        for (int f = 0; f < 5; ++f) lds[wv][f][4 + k] = 0.f;
    }
    if (k >= 60) {
        #pragma unroll
        for (int f = 0; f < 5; ++f) lds[wv][f][200 + (k - 60)] = 0.f;
    }

    const float* Ib = I + (size_t)c*VOL + (size_t)d*HWN + w0;
    const float* Jb = J + (size_t)c*VOL + (size_t)d*HWN + w0;

    float4 rs0=zero4(), rs1=zero4(), rs2=zero4(), rs3=zero4(), rs4=zero4();
    float4 rI0,rI1,rI2,rI3,rI4,rI5,rI6,rI7,rI8, rJ0,rJ1,rJ2,rJ3,rJ4,rJ5,rJ6,rJ7,rJ8;
    rI8 = zero4(); rJ8 = zero4();

    // warm-up: ring slots 0..7 = I/J rows h0-4 .. h0+3 (zero padded)
    #define WARM(S, RIS, RJS) { const int h = h0 - RAD + S;                        \
        float4 iv = zero4(), jv = zero4();                                         \
        if (act && h >= 0 && h < HDIM) {                                           \
            iv = *(const float4*)(Ib + (size_t)h*WDIM);                            \
            jv = *(const float4*)(Jb + (size_t)h*WDIM); }                          \
        RIS = iv; RJS = jv; padd(rs0,rs1,rs2,rs3,rs4, iv, jv); }
    WARM(0,rI0,rJ0) WARM(1,rI1,rJ1) WARM(2,rI2,rJ2) WARM(3,rI3,rJ3)
    WARM(4,rI4,rJ4) WARM(5,rI5,rJ5) WARM(6,rI6,rJ6) WARM(7,rI7,rJ7)
    #undef WARM

    // prefetch step-0 add row (h0+4 < 224 always)
    float4 nI = zero4(), nJ = zero4();
    if (act) {
        nI = *(const float4*)(Ib + (size_t)(h0 + RAD)*WDIM);
        nJ = *(const float4*)(Jb + (size_t)(h0 + RAD)*WDIM);
    }

    const size_t fstride = (size_t)C2*bufD*HWN;
    __half* ob = buf + ((size_t)c*bufD + (size_t)(d - d0 + RAD))*HWN + w0;

    float4* const L0 = (float4*)&lds[wv][0][0];
    float4* const L1 = (float4*)&lds[wv][1][0];
    float4* const L2 = (float4*)&lds[wv][2][0];
    float4* const L3 = (float4*)&lds[wv][3][0];
    float4* const L4 = (float4*)&lds[wv][4][0];

    int i = 0;

    // A = left neighbor's 4 H-sums, RSF = own (register, no LDS re-read),
    // C = right neighbor's. Rolling 9-tap over [w-4 .. w+7].
    #define FIELDOUT(L, RSF, F) {                                                  \
        const float4 A = L[k+1], Cc = L[k+3];                                      \
        const float o0 = ((A.x+A.y)+(A.z+A.w)) + ((RSF.x+RSF.y)+(RSF.z+RSF.w)) + Cc.x; \
        const float o1 = o0 - A.x + Cc.y;                                          \
        const float o2 = o1 - A.y + Cc.z;                                          \
        const float o3 = o2 - A.z + Cc.w;                                          \
        const __half2 ha = __floats2half2_rn(o0, o1);                              \
        const __half2 hb = __floats2half2_rn(o2, o3);                              \
        uint2 u; u.x = __builtin_bit_cast(unsigned int, ha);                       \
        u.y = __builtin_bit_cast(unsigned int, hb);                                \
        *reinterpret_cast<uint2*>(ob + (size_t)F*fstride + (size_t)h*WDIM) = u; }

    #define STEP(RID, RJD, RIS, RJS) {                                             \
        const int h = h0 + i;                                                      \
        const float4 aI = nI, aJ = nJ;                                             \
        nI = zero4(); nJ = zero4();                                                \
        { const int hf = h + 1 + RAD;                                              \
          if (act && (i + 1 < HT1) && hf < HDIM) {                                 \
              nI = *(const float4*)(Ib + (size_t)hf*WDIM);                         \
              nJ = *(const float4*)(Jb + (size_t)hf*WDIM); } }                     \
        padd(rs0,rs1,rs2,rs3,rs4, aI, aJ);                                         \
        if (act) { L0[k+2]=rs0; L1[k+2]=rs1; L2[k+2]=rs2; L3[k+2]=rs3; L4[k+2]=rs4; } \
        asm volatile("s_waitcnt lgkmcnt(0)" ::: "memory");                         \
        if (act) { FIELDOUT(L0,rs0,0) FIELDOUT(L1,rs1,1) FIELDOUT(L2,rs2,2)        \
                   FIELDOUT(L3,rs3,3) FIELDOUT(L4,rs4,4) }                         \
        psub(rs0,rs1,rs2,rs3,rs4, RID, RJD);                                       \
        RIS = aI; RJS = aJ;                                                        \
        ++i; }

    for (int s = 0; s < 3; ++s) {          // 27 steps: 3 x 9 phases
        STEP(rI0,rJ0,rI8,rJ8) STEP(rI1,rJ1,rI0,rJ0) STEP(rI2,rJ2,rI1,rJ1)
        STEP(rI3,rJ3,rI2,rJ2) STEP(rI4,rJ4,rI3,rJ3) STEP(rI5,rJ5,rI4,rJ4)
        STEP(rI6,rJ6,rI5,rJ5) STEP(rI7,rJ7,rI6,rJ6) STEP(rI8,rJ8,rI7,rJ7)
    }
    STEP(rI0,rJ0,rI8,rJ8)                  // step 28 (phase 0)
    #undef STEP
    #undef FIELDOUT
}

// -------- K2: D-sum (register ring) + cc + block reduce — no LDS, no syncs --------
// grid: (HWN/256, nsub, C2); block: 256 threads
__global__ __launch_bounds__(256)
void k_dsum(const __half* __restrict__ buf, double* __restrict__ gacc,
            int d0, int bufD, int DS)
{
    const int tid = threadIdx.x;
    const int pix = blockIdx.x*256 + tid;     // (h,w) flat, HWN = 168*256 exact
    const int c   = blockIdx.z;
    const int ds0 = d0 + blockIdx.y*DS;

    const size_t fstride = (size_t)C2*bufD*HWN;
    const __half* base = buf + (size_t)c*bufD*HWN + pix;

    float ring[5][9];
    float rs[5] = {0.f,0.f,0.f,0.f,0.f};
    float acc = 0.f;

    // warm-up: slices ds0-4 .. ds0+3
    #pragma unroll
    for (int k = 0; k < 8; ++k) {
        const int dd = ds0 - RAD + k;
        float v[5] = {0.f,0.f,0.f,0.f,0.f};
        if ((unsigned)dd < (unsigned)DDIM) {
            const __half* pp = base + (size_t)(dd - d0 + RAD)*HWN;
            #pragma unroll
            for (int f = 0; f < 5; ++f) v[f] = __half2float(pp[(size_t)f*fstride]);
        }
        #pragma unroll
        for (int f = 0; f < 5; ++f) { ring[f][k] = v[f]; rs[f] += v[f]; }
    }

    int i = 0;
    while (i < DS) {
        #pragma unroll
        for (int p = 0; p < 9; ++p) {   // i == p (mod 9) whenever body runs
            if (i < DS) {
                const int dd = ds0 + i + RAD;
                float v[5] = {0.f,0.f,0.f,0.f,0.f};
                if (dd < DDIM) {
                    const __half* pp = base + (size_t)(dd - d0 + RAD)*HWN;
                    #pragma unroll
                    for (int f = 0; f < 5; ++f) v[f] = __half2float(pp[(size_t)f*fstride]);
                }
                float S[5];
                #pragma unroll
                for (int f = 0; f < 5; ++f) {
                    rs[f] += v[f];              // full 9x9x9 sum at dd-4
                    S[f] = rs[f];
                    rs[f] -= ring[f][p];        // drop slice dd-8
                    ring[f][(p+8)%9] = v[f];    // keep slice dd
                }
                const float uI    = S[0]*WINV;
                const float uJ    = S[1]*WINV;
                const float cross = S[4] - uJ*S[0];
                const float Iv    = S[2] - uI*S[0];
                const float Jv    = S[3] - uJ*S[1];
                acc += cross*cross / (Iv*Jv + 1e-5f);
                ++i;
            }
        }
    }

    // block reduction -> one double atomic per block
    __shared__ float wred[4];
    #pragma unroll
    for (int off = 32; off > 0; off >>= 1) acc += __shfl_down(acc, off);
    if ((tid & 63) == 0) wred[tid >> 6] = acc;
    __syncthreads();
    if (tid == 0) {
        const float sum = wred[0] + wred[1] + wred[2] + wred[3];
        atomicAdd(gacc, (double)sum);
    }
}

__global__ void k_fin(const double* __restrict__ gacc, float* __restrict__ out)
{
    out[0] = (float)(-gacc[0] / (double)((size_t)C2*DDIM*HDIM*WDIM));
}

extern "C" void kernel_launch(void* const* d_in, const int* in_sizes, int n_in,
                              void* d_out, int out_size, void* d_ws, size_t ws_size,
                              hipStream_t stream)
{
    if (n_in < 2) return;
    const float* I = (const float*)d_in[0];
    const float* J = (const float*)d_in[1];
    float* out = (float*)d_out;
    double* gacc = (double*)d_ws;
    __half* buf = (__half*)((char*)d_ws + 256);

    // choose D-chunk so the 5-field fp16 2D-summed buffer fits ws (192 = 1 chunk)
    static const int cands[] = {192, 96, 48, 24, 12, 6, 4, 2, 1};
    int Dc = 0;
    for (int c : cands) {
        const size_t need = 256 + (size_t)5*C2*(c+8)*HWN*sizeof(__half);
        if (need <= ws_size) { Dc = c; break; }
    }
    if (Dc == 0) return;  // ws too small — cannot run

    hipMemsetAsync(d_ws, 0, 256, stream);   // zero the double accumulator

    const int DS   = (Dc % 48 == 0) ? 48 : Dc;  // K2 sub-chunk along D
    const int nsub = Dc / DS;
    const int bufD = Dc + 8;

    for (int d0 = 0; d0 < DDIM; d0 += Dc) {
        const int dbeg = (d0 - RAD < 0) ? 0 : d0 - RAD;
        const int dend = (d0 + Dc + RAD > DDIM) ? DDIM : d0 + Dc + RAD;
        const int nd   = dend - dbeg;
        dim3 g1((nd + 3)/4, HDIM/HT1, C2);
        k_hwsum<<<g1, dim3(256,1,1), 0, stream>>>(I, J, buf, d0, dbeg, dend, bufD);
        dim3 g2(HWN/256, nsub, C2);
        k_dsum<<<g2, dim3(256,1,1), 0, stream>>>(buf, gacc, d0, bufD, DS);
    }
    k_fin<<<1,1,0,stream>>>(gacc, out);
}